// Round 18
// baseline (818.840 us; speedup 1.0000x reference)
//
#include <hip/hip_runtime.h>
#include <hip/hip_bf16.h>

// ---------------------------------------------------------------------------
// WinEncoderTransformer, multi-kernel pipeline, bf16 activations end-to-end.
// R17: BN=64 for the three fat GEMMs (qkv2, h, f): LDS 48->24 KB doubles
// occupancy (3->6 blocks/CU) to cover L2 latency — the R15 counters showed
// these latency-bound at ~19% occupancy. Bit-identical accumulation order.
// Kept: register-prefetch gemm, XCD remap + grid transpose, merged qkv+Wlq,
// hifi+pool union, merged hilo projection, fused LN tails. absmax: 0.0625.
// ---------------------------------------------------------------------------

#define RT 131072ull
#define ATT_SCALE 0.17677669529663687f   // 32^-0.5

typedef float f32x4 __attribute__((ext_vector_type(4)));
typedef __bf16 bf16x8 __attribute__((ext_vector_type(8)));
typedef unsigned short u16x8 __attribute__((ext_vector_type(8)));
typedef unsigned short u16x4 __attribute__((ext_vector_type(4)));

__device__ __forceinline__ unsigned short f2bf(float f) {
    unsigned int u = __float_as_uint(f);
    return (unsigned short)((u + 0x7FFFu + ((u >> 16) & 1u)) >> 16);  // RNE
}
__device__ __forceinline__ float bf2f(unsigned short s) {
    return __uint_as_float(((unsigned int)s) << 16);
}

// ---------------------------------------------------------------------------
// weight prep: src [L][K][N] f32 -> dst + l*ldd, [N][K] bf16 (transposed)
// ---------------------------------------------------------------------------
__global__ __launch_bounds__(256) void wprep(const float* __restrict__ src,
                                             unsigned short* __restrict__ dst,
                                             int K, int N, int ldd)
{
    __shared__ unsigned short t[32][33];
    int l = blockIdx.z;
    const float* s = src + (size_t)l * K * N;
    unsigned short* d = dst + (size_t)l * ldd;
    int r = threadIdx.x >> 3, c4 = (threadIdx.x & 7) * 4;
    int kb = blockIdx.x * 32, nb = blockIdx.y * 32;
    f32x4 v = *(const f32x4*)(s + (size_t)(kb + r) * N + nb + c4);
    #pragma unroll
    for (int j = 0; j < 4; ++j) t[c4 + j][r] = f2bf(v[j]);
    __syncthreads();
    u16x4 o;
    #pragma unroll
    for (int j = 0; j < 4; ++j) o[j] = t[r][c4 + j];
    *(u16x4*)(d + (size_t)(nb + r) * K + kb + c4) = o;
}

// ---------------------------------------------------------------------------
// cvt: tgt f32 -> x bf16
// ---------------------------------------------------------------------------
__global__ __launch_bounds__(256) void cvt_bf16(const float* __restrict__ src,
                                                unsigned short* __restrict__ dst)
{
    size_t i = ((size_t)blockIdx.x * 256 + threadIdx.x) * 8;
    f32x4 a = *(const f32x4*)(src + i);
    f32x4 b = *(const f32x4*)(src + i + 4);
    u16x8 t;
    #pragma unroll
    for (int j = 0; j < 4; ++j) { t[j] = f2bf(a[j]); t[4 + j] = f2bf(b[j]); }
    *(u16x8*)(dst + i) = t;
}

// ---------------------------------------------------------------------------
// GEMM device body: C[M x N] = A @ BT^T (+bias)(+relu), bf16, MFMA.
// BM=128, BN templated (64: 24KB LDS -> 6 blocks/CU; 128: 48KB -> 3),
// BK=64, 256 threads (2x2 waves). XOR-swizzled LDS, single LDS buffer +
// register prefetch (tile t+1 loads issue under compute(t)).
// ---------------------------------------------------------------------------
template<int BN, bool BIAS, bool RELU>
__device__ __forceinline__ void gemm_body(
    const unsigned short* __restrict__ A, int lda, size_t m0,
    const unsigned short* __restrict__ BT, int n0,
    const float* __restrict__ bias,
    unsigned short* __restrict__ C, int ldc, int K)
{
    constexpr int NT = BN / 32;
    constexpr int BCH = BN / 32;
    __shared__ __align__(16) char As[128 * 128];
    __shared__ __align__(16) char Bs[BN * 128];

    const int tid = threadIdx.x;
    const int w = tid >> 6, l = tid & 63;
    const int lr = l & 15, lk = l >> 4;
    const int wm = w >> 1, wn = w & 1;

    f32x4 acc[4][NT] = {};
    u16x8 ra[4], rb[BCH];

    auto gload = [&](int k0) {
        #pragma unroll
        for (int i = 0; i < 4; ++i) {
            int cid = tid + i * 256, row = cid >> 3, kc = cid & 7;
            ra[i] = *(const u16x8*)(A + (m0 + row) * lda + k0 + kc * 8);
        }
        #pragma unroll
        for (int i = 0; i < BCH; ++i) {
            int fid = tid + i * 256, row = fid >> 3, kc = fid & 7;
            rb[i] = *(const u16x8*)(BT + (size_t)(n0 + row) * K + k0 + kc * 8);
        }
    };
    auto lstore = [&]() {
        #pragma unroll
        for (int i = 0; i < 4; ++i) {
            int cid = tid + i * 256, row = cid >> 3, kc = cid & 7;
            *(u16x8*)(As + ((row * 128 + kc * 16) ^ ((row & 7) << 4))) = ra[i];
        }
        #pragma unroll
        for (int i = 0; i < BCH; ++i) {
            int fid = tid + i * 256, row = fid >> 3, kc = fid & 7;
            *(u16x8*)(Bs + ((row * 128 + kc * 16) ^ ((row & 7) << 4))) = rb[i];
        }
    };

    const int nk = K >> 6;
    gload(0);
    for (int t = 0; t < nk; ++t) {
        lstore();
        __syncthreads();
        if (t + 1 < nk) gload((t + 1) << 6);
        #pragma unroll
        for (int s = 0; s < 2; ++s) {
            bf16x8 bfr[NT];
            #pragma unroll
            for (int nt = 0; nt < NT; ++nt) {
                int r = wn * (BN / 2) + nt * 16 + lr;
                bfr[nt] = *(const bf16x8*)(Bs + ((r * 128 + s * 64 + lk * 16) ^ ((r & 7) << 4)));
            }
            #pragma unroll
            for (int mt = 0; mt < 4; ++mt) {
                int r = wm * 64 + mt * 16 + lr;
                bf16x8 afr = *(const bf16x8*)(As + ((r * 128 + s * 64 + lk * 16) ^ ((r & 7) << 4)));
                #pragma unroll
                for (int nt = 0; nt < NT; ++nt)
                    acc[mt][nt] = __builtin_amdgcn_mfma_f32_16x16x32_bf16(afr, bfr[nt], acc[mt][nt], 0, 0, 0);
            }
        }
        __syncthreads();
    }
    #pragma unroll
    for (int nt = 0; nt < NT; ++nt) {
        int col = n0 + wn * (BN / 2) + nt * 16 + lr;
        float bv = BIAS ? bias[col] : 0.0f;
        #pragma unroll
        for (int mt = 0; mt < 4; ++mt) {
            #pragma unroll
            for (int j = 0; j < 4; ++j) {
                size_t row = m0 + (size_t)(wm * 64 + mt * 16 + lk * 4 + j);
                float v = acc[mt][nt][j] + bv;
                if (RELU) v = fmaxf(v, 0.0f);
                C[row * ldc + col] = f2bf(v);
            }
        }
    }
}

// standard GEMM: XCD-aware remap (bijective: all grids have nwg % 8 == 0),
// n-tile fast within an m-panel, each XCD owns contiguous m-panels.
template<int BN, bool BIAS, bool RELU>
__global__ __launch_bounds__(256) void gemm_bb(
    const unsigned short* __restrict__ A, int lda,
    const unsigned short* __restrict__ BT,
    const float* __restrict__ bias,
    unsigned short* __restrict__ C, int ldc, int K)
{
    const int hw = blockIdx.x + gridDim.x * blockIdx.y;
    const int nwg = gridDim.x * gridDim.y;
    const int logical = (hw & 7) * (nwg >> 3) + (hw >> 3);
    const int n0 = (logical % gridDim.x) * BN;
    const size_t m0 = (size_t)(logical / gridDim.x) * 128;
    gemm_body<BN, BIAS, RELU>(A, lda, m0, BT, n0, bias, C, ldc, K);
}

// merged hi/lo projection: grid (1, 2048); logical m-panels >= 1024 compute
// lo = los @ WlpT + blp, else hi = os @ WhpT + bhp. K=128, BN=128, ldc=128.
__global__ __launch_bounds__(256) void gemm_hilo(
    const unsigned short* __restrict__ os,
    const unsigned short* __restrict__ los,
    const unsigned short* __restrict__ tWhp,
    const unsigned short* __restrict__ tWlp,
    const float* __restrict__ bhp, const float* __restrict__ blp,
    unsigned short* __restrict__ hi, unsigned short* __restrict__ lo)
{
    const int hw = blockIdx.x + gridDim.x * blockIdx.y;
    const int nwg = gridDim.x * gridDim.y;
    const int logical = (hw & 7) * (nwg >> 3) + (hw >> 3);
    size_t mp = (size_t)logical;
    const unsigned short* A;
    const unsigned short* BT;
    const float* bias;
    unsigned short* C;
    if (mp < 1024) {
        A = os;  BT = tWhp; bias = bhp; C = hi;
    } else {
        A = los; BT = tWlp; bias = blp; C = lo; mp -= 1024;
    }
    gemm_body<128, true, false>(A, 128, mp * 128, BT, 0, bias, C, 128, 128);
}

// ---------------------------------------------------------------------------
// hifi_pool: grid union. Blocks [0,2048): windowed 4-token attention from
// qkv2 (row stride 512: [q|k|v|lq]). Blocks [2048,6144): 2x2 window pooling.
// ---------------------------------------------------------------------------
__global__ __launch_bounds__(256) void hifi_pool(
    const unsigned short* __restrict__ qkv,
    unsigned short* __restrict__ os,
    const unsigned short* __restrict__ x,
    unsigned short* __restrict__ xp)
{
    if (blockIdx.x < 2048) {
        int t = blockIdx.x * 256 + threadIdx.x;
        int wdw = t >> 4, h = (t >> 2) & 3, qi = t & 3;
        int bc = wdw >> 5, tw = wdw & 31;
        int rbase = bc * 128 + (tw >> 3) * 32 + (tw & 7) * 2;
        int qrow = rbase + ((qi >> 1) << 4) + (qi & 1);

        const unsigned short* qp = qkv + (size_t)qrow * 512 + h * 32;
        float q[32];
        #pragma unroll
        for (int c = 0; c < 4; ++c) {
            u16x8 v = *(const u16x8*)(qp + c * 8);
            #pragma unroll
            for (int j = 0; j < 8; ++j) q[c * 8 + j] = bf2f(v[j]);
        }
        float s4[4];
        #pragma unroll
        for (int j = 0; j < 4; ++j) {
            int kr = rbase + ((j >> 1) << 4) + (j & 1);
            const unsigned short* kp = qkv + (size_t)kr * 512 + 128 + h * 32;
            float d = 0.0f;
            #pragma unroll
            for (int c = 0; c < 4; ++c) {
                u16x8 v = *(const u16x8*)(kp + c * 8);
                #pragma unroll
                for (int jj = 0; jj < 8; ++jj) d += q[c * 8 + jj] * bf2f(v[jj]);
            }
            s4[j] = d * ATT_SCALE;
        }
        float mx = fmaxf(fmaxf(s4[0], s4[1]), fmaxf(s4[2], s4[3]));
        float den = 0.0f;
        #pragma unroll
        for (int j = 0; j < 4; ++j) { s4[j] = __expf(s4[j] - mx); den += s4[j]; }
        float inv = 1.0f / den;

        float o[32];
        #pragma unroll
        for (int i = 0; i < 32; ++i) o[i] = 0.0f;
        #pragma unroll
        for (int j = 0; j < 4; ++j) {
            int vr = rbase + ((j >> 1) << 4) + (j & 1);
            const unsigned short* vp = qkv + (size_t)vr * 512 + 256 + h * 32;
            float a = s4[j] * inv;
            #pragma unroll
            for (int c = 0; c < 4; ++c) {
                u16x8 v = *(const u16x8*)(vp + c * 8);
                #pragma unroll
                for (int jj = 0; jj < 8; ++jj) o[c * 8 + jj] += a * bf2f(v[jj]);
            }
        }
        unsigned short* op = os + (size_t)qrow * 128 + h * 32;
        #pragma unroll
        for (int c = 0; c < 4; ++c) {
            u16x8 v;
            #pragma unroll
            for (int j = 0; j < 8; ++j) v[j] = f2bf(o[c * 8 + j]);
            *(u16x8*)(op + c * 8) = v;
        }
    } else {
        int id = (blockIdx.x - 2048) * 256 + threadIdx.x;
        int p = id >> 5, c8 = (id & 31) * 8;
        int bc = p >> 5, tw = p & 31;
        int rbase = bc * 128 + (tw >> 3) * 32 + (tw & 7) * 2;
        const unsigned short* x0 = x + (size_t)rbase * 256 + c8;
        float a[8] = {};
        const int offs[4] = {0, 256, 16 * 256, 17 * 256};
        #pragma unroll
        for (int r = 0; r < 4; ++r) {
            u16x8 v = *(const u16x8*)(x0 + offs[r]);
            #pragma unroll
            for (int j = 0; j < 8; ++j) a[j] += bf2f(v[j]);
        }
        u16x8 o;
        #pragma unroll
        for (int j = 0; j < 8; ++j) o[j] = f2bf(a[j] * 0.25f);
        *(u16x8*)(xp + (size_t)p * 256 + c8) = o;
    }
}

// ---------------------------------------------------------------------------
// lofi: 128 queries vs 32 pooled kv per (bc, head). q from qkv2 (ldq=512).
// ---------------------------------------------------------------------------
__global__ __launch_bounds__(128) void lofi_attn(const unsigned short* __restrict__ qb,
                                                 int ldq,
                                                 const unsigned short* __restrict__ kvb,
                                                 unsigned short* __restrict__ ob)
{
    __shared__ float ks[32][36];
    __shared__ float vs[32][36];
    int bc = blockIdx.x >> 2, h = blockIdx.x & 3;
    int tid = threadIdx.x;

    #pragma unroll
    for (int i = 0; i < 2; ++i) {
        int fid = tid + i * 128;
        int row = fid >> 3, cc = (fid & 7) * 4;
        const unsigned short* kp = kvb + (size_t)(bc * 32 + row) * 256 + h * 32 + cc;
        u16x4 kk = *(const u16x4*)kp;
        u16x4 vv = *(const u16x4*)(kp + 128);
        #pragma unroll
        for (int j = 0; j < 4; ++j) { ks[row][cc + j] = bf2f(kk[j]); vs[row][cc + j] = bf2f(vv[j]); }
    }

    const unsigned short* qp = qb + (size_t)(bc * 128 + tid) * ldq + h * 32;
    float q[32];
    #pragma unroll
    for (int c = 0; c < 4; ++c) {
        u16x8 v = *(const u16x8*)(qp + c * 8);
        #pragma unroll
        for (int j = 0; j < 8; ++j) q[c * 8 + j] = bf2f(v[j]);
    }
    __syncthreads();

    float sc[32];
    #pragma unroll
    for (int tk = 0; tk < 32; ++tk) {
        float d = 0.0f;
        #pragma unroll
        for (int i = 0; i < 32; ++i) d += q[i] * ks[tk][i];
        sc[tk] = d * ATT_SCALE;
    }
    float mx = -1e30f;
    #pragma unroll
    for (int tk = 0; tk < 32; ++tk) mx = fmaxf(mx, sc[tk]);
    float den = 0.0f;
    #pragma unroll
    for (int tk = 0; tk < 32; ++tk) { sc[tk] = __expf(sc[tk] - mx); den += sc[tk]; }
    float inv = 1.0f / den;

    float o[32];
    #pragma unroll
    for (int i = 0; i < 32; ++i) o[i] = 0.0f;
    #pragma unroll
    for (int tk = 0; tk < 32; ++tk) {
        float a = sc[tk];
        #pragma unroll
        for (int i = 0; i < 32; ++i) o[i] += a * vs[tk][i];
    }
    unsigned short* op = ob + (size_t)(bc * 128 + tid) * 128 + h * 32;
    #pragma unroll
    for (int c = 0; c < 4; ++c) {
        u16x8 v;
        #pragma unroll
        for (int j = 0; j < 8; ++j) v[j] = f2bf(o[c * 8 + j] * inv);
        *(u16x8*)(op + c * 8) = v;
    }
}

// ---------------------------------------------------------------------------
// addln: one 64-lane wave per row (4 rows/block), lane holds 4 cols.
// MODE 0: x + [hi|lo] -> LN -> x bf16
// MODE 1: x + f       -> LN -> x bf16
// MODE 2: x + f -> LN2 -> LNf -> out f32 (fused tail, f32 precision)
// ---------------------------------------------------------------------------
template<int MODE>
__global__ __launch_bounds__(256) void addln(
    const unsigned short* __restrict__ x,
    const unsigned short* __restrict__ r1,
    const unsigned short* __restrict__ r2,
    const float* __restrict__ g, const float* __restrict__ b,
    const float* __restrict__ g2, const float* __restrict__ b2,
    unsigned short* __restrict__ xout, float* __restrict__ fout)
{
    size_t row = (size_t)blockIdx.x * 4 + (threadIdx.x >> 6);
    int l = threadIdx.x & 63;
    u16x4 xv = *(const u16x4*)(x + row * 256 + l * 4);
    f32x4 v;
    #pragma unroll
    for (int j = 0; j < 4; ++j) v[j] = bf2f(xv[j]);
    if (MODE == 0) {
        const unsigned short* rp = (l < 32) ? (r1 + row * 128 + l * 4)
                                            : (r2 + row * 128 + (l - 32) * 4);
        u16x4 rv = *(const u16x4*)rp;
        #pragma unroll
        for (int j = 0; j < 4; ++j) v[j] += bf2f(rv[j]);
    } else {
        u16x4 rv = *(const u16x4*)(r1 + row * 256 + l * 4);
        #pragma unroll
        for (int j = 0; j < 4; ++j) v[j] += bf2f(rv[j]);
    }
    float s = v[0] + v[1] + v[2] + v[3];
    float sq = v[0] * v[0] + v[1] * v[1] + v[2] * v[2] + v[3] * v[3];
    #pragma unroll
    for (int off = 32; off > 0; off >>= 1) { s += __shfl_xor(s, off); sq += __shfl_xor(sq, off); }
    float mean = s * (1.0f / 256.0f);
    float rstd = rsqrtf(sq * (1.0f / 256.0f) - mean * mean + 1e-5f);
    f32x4 gv = *(const f32x4*)(g + l * 4);
    f32x4 bv = *(const f32x4*)(b + l * 4);
    f32x4 o;
    #pragma unroll
    for (int j = 0; j < 4; ++j) o[j] = (v[j] - mean) * rstd * gv[j] + bv[j];
    if (MODE == 2) {
        float s2 = o[0] + o[1] + o[2] + o[3];
        float sq2 = o[0] * o[0] + o[1] * o[1] + o[2] * o[2] + o[3] * o[3];
        #pragma unroll
        for (int off = 32; off > 0; off >>= 1) { s2 += __shfl_xor(s2, off); sq2 += __shfl_xor(sq2, off); }
        float mean2 = s2 * (1.0f / 256.0f);
        float rstd2 = rsqrtf(sq2 * (1.0f / 256.0f) - mean2 * mean2 + 1e-5f);
        f32x4 g2v = *(const f32x4*)(g2 + l * 4);
        f32x4 b2v = *(const f32x4*)(b2 + l * 4);
        f32x4 f;
        #pragma unroll
        for (int j = 0; j < 4; ++j) f[j] = (o[j] - mean2) * rstd2 * g2v[j] + b2v[j];
        *(f32x4*)(fout + row * 256 + l * 4) = f;
    } else {
        u16x4 t;
        #pragma unroll
        for (int j = 0; j < 4; ++j) t[j] = f2bf(o[j]);
        *(u16x4*)(xout + row * 256 + l * 4) = t;
    }
}

// ---------------------------------------------------------------------------
extern "C" void kernel_launch(void* const* d_in, const int* in_sizes, int n_in,
                              void* d_out, int out_size, void* d_ws, size_t ws_size,
                              hipStream_t stream)
{
    (void)in_sizes; (void)n_in; (void)out_size; (void)ws_size;
    const float* tgt   = (const float*)d_in[0];
    const float* Wlq   = (const float*)d_in[1];
    const float* Wlkv  = (const float*)d_in[2];
    const float* Wlp   = (const float*)d_in[3];
    const float* blp   = (const float*)d_in[4];
    const float* Whqkv = (const float*)d_in[5];
    const float* Whp   = (const float*)d_in[6];
    const float* bhp   = (const float*)d_in[7];
    const float* W1    = (const float*)d_in[8];
    const float* b1    = (const float*)d_in[9];
    const float* W2    = (const float*)d_in[10];
    const float* b2    = (const float*)d_in[11];
    const float* ln1g  = (const float*)d_in[12];
    const float* ln1b  = (const float*)d_in[13];
    const float* ln2g  = (const float*)d_in[14];
    const float* ln2b  = (const float*)d_in[15];
    const float* lnfg  = (const float*)d_in[16];
    const float* lnfb  = (const float*)d_in[17];

    unsigned short* wsu = (unsigned short*)d_ws;
    // transposed bf16 weights: tQ = [Whqkv | Wlq] combined [L][512][256]
    unsigned short* tQ     = wsu;             // 2*512*256 = 262144
    unsigned short* tWhp   = wsu + 262144;    // 2*128*128 =  32768
    unsigned short* tWlkv  = wsu + 294912;    // 2*256*256 = 131072
    unsigned short* tWlp   = wsu + 425984;    // 2*128*128 =  32768
    unsigned short* tW1    = wsu + 458752;    // 2*512*256 = 262144
    unsigned short* tW2    = wsu + 720896;    // 2*256*512 = 262144
    unsigned short* x      = wsu + 983040;               // R*256
    unsigned short* qkv2   = x + RT * 256;               // R*512 [q|k|v|lq]
    unsigned short* f      = qkv2;                       // R*256 alias (qkv2 dead after lofi)
    unsigned short* xp     = qkv2 + RT * 512;            // 32768*256
    unsigned short* kv     = xp + 32768ull * 256;        // 32768*256
    unsigned short* hbuf   = kv + 32768ull * 256;        // R*512
    unsigned short* los    = hbuf;                       // R*128
    unsigned short* os     = hbuf + RT * 128;            // R*128
    unsigned short* hi     = hbuf + RT * 256;            // R*128
    unsigned short* lo     = hbuf + RT * 384;            // R*128
    // lifetime: {los,os,hi,lo} all dead after addln0; then hbuf holds h.

    wprep<<<dim3(8, 12, 2), 256, 0, stream>>>(Whqkv, tQ, 256, 384, 131072);
    wprep<<<dim3(8,  4, 2), 256, 0, stream>>>(Wlq, tQ + 98304, 256, 128, 131072);
    wprep<<<dim3(4,  4, 2), 256, 0, stream>>>(Whp,  tWhp,  128, 128, 16384);
    wprep<<<dim3(8,  8, 2), 256, 0, stream>>>(Wlkv, tWlkv, 256, 256, 65536);
    wprep<<<dim3(4,  4, 2), 256, 0, stream>>>(Wlp,  tWlp,  128, 128, 16384);
    wprep<<<dim3(8, 16, 2), 256, 0, stream>>>(W1,   tW1,   256, 512, 131072);
    wprep<<<dim3(16, 8, 2), 256, 0, stream>>>(W2,   tW2,   512, 256, 131072);

    cvt_bf16<<<16384, 256, 0, stream>>>(tgt, x);

    for (int li = 0; li < 2; ++li) {
        // 1. qkv2 = x @ [Whqkv|Wlq]T  (R x 512, K=256; BN=64, nwg=8192)
        gemm_bb<64, false, false><<<dim3(8, 1024), 256, 0, stream>>>(
            x, 256, tQ + (size_t)li * 131072, nullptr, qkv2, 512, 256);
        // 2. hifi window attention + pool (grid union)
        hifi_pool<<<6144, 256, 0, stream>>>(qkv2, os, x, xp);
        // 3. kv = xp @ WlkvT   (M = 32768, BN=128, nwg=512)
        gemm_bb<128, false, false><<<dim3(2, 256), 256, 0, stream>>>(
            xp, 256, tWlkv + (size_t)li * 65536, nullptr, kv, 256, 256);
        // 4. lofi attention (q = qkv2 cols 384.., stride 512) -> los
        lofi_attn<<<4096, 128, 0, stream>>>(qkv2 + 384, 512, kv, los);
        // 5. merged hi/lo projection (BN=128, nwg=2048)
        gemm_hilo<<<dim3(1, 2048), 256, 0, stream>>>(
            os, los, tWhp + (size_t)li * 16384, tWlp + (size_t)li * 16384,
            bhp + li * 128, blp + li * 128, hi, lo);
        // 6. x = LN(x + [hi|lo])
        addln<0><<<32768, 256, 0, stream>>>(x, hi, lo, ln1g + li * 256, ln1b + li * 256,
                                            nullptr, nullptr, x, nullptr);
        // 7. h = relu(x @ W1T + b1)   (BN=64, nwg=8192)
        gemm_bb<64, true, true><<<dim3(8, 1024), 256, 0, stream>>>(
            x, 256, tW1 + (size_t)li * 131072, b1 + li * 512, hbuf, 512, 256);
        // 8. f = h @ W2T + b2   (f aliases qkv2[0:R*256]; BN=64, nwg=4096)
        gemm_bb<64, true, false><<<dim3(4, 1024), 256, 0, stream>>>(
            hbuf, 512, tW2 + (size_t)li * 131072, b2 + li * 256, f, 256, 512);
        // 9. x = LN(x + f)  |  layer 1: fused LN2 + final LN -> f32 out
        if (li == 0) {
            addln<1><<<32768, 256, 0, stream>>>(x, f, nullptr, ln2g, ln2b,
                                                nullptr, nullptr, x, nullptr);
        } else {
            addln<2><<<32768, 256, 0, stream>>>(x, f, nullptr, ln2g + 256, ln2b + 256,
                                                lnfg, lnfb, nullptr, (float*)d_out);
        }
    }
}

// Round 19
// 784.710 us; speedup vs baseline: 1.0435x; 1.0435x over previous
//
#include <hip/hip_runtime.h>
#include <hip/hip_bf16.h>

// ---------------------------------------------------------------------------
// WinEncoderTransformer, multi-kernel pipeline, bf16 activations end-to-end.
// R18: (1) BN reverted to 128 (R17 exact: BN=64 regressed 799->819 — latency
// is NOT binding; gap is ramp/tail overhead). (2) the 7 wprep dispatches are
// merged into one wprep_all (960 blocks, descriptor table) — removes ~6
// launch ramps from the prologue. Everything else identical to the 799 µs
// R17 build: register-prefetch gemm, XCD remap + grid transpose, merged
// qkv+Wlq, hifi+pool union, merged hilo projection, fused LN tails.
// ---------------------------------------------------------------------------

#define RT 131072ull
#define ATT_SCALE 0.17677669529663687f   // 32^-0.5

typedef float f32x4 __attribute__((ext_vector_type(4)));
typedef __bf16 bf16x8 __attribute__((ext_vector_type(8)));
typedef unsigned short u16x8 __attribute__((ext_vector_type(8)));
typedef unsigned short u16x4 __attribute__((ext_vector_type(4)));

__device__ __forceinline__ unsigned short f2bf(float f) {
    unsigned int u = __float_as_uint(f);
    return (unsigned short)((u + 0x7FFFu + ((u >> 16) & 1u)) >> 16);  // RNE
}
__device__ __forceinline__ float bf2f(unsigned short s) {
    return __uint_as_float(((unsigned int)s) << 16);
}

// ---------------------------------------------------------------------------
// wprep_all: all weight transposes in ONE dispatch. Descriptor per matrix:
// src [L=2][K][N] f32 -> dst + l*ldd as [N][K] bf16. Segment lookup by bid.
// ---------------------------------------------------------------------------
struct WDesc {
    const float* src;
    unsigned short* dst;
    int K, N, ldd, nx, ny, off;   // nx = K/32 tiles, ny = N/32 tiles
};
struct W7 { WDesc d[7]; };

__global__ __launch_bounds__(256) void wprep_all(W7 w)
{
    __shared__ unsigned short t[32][33];
    int bid = blockIdx.x;
    int seg = 0;
    #pragma unroll
    for (int i = 1; i < 7; ++i) if (bid >= w.d[i].off) seg = i;
    const WDesc& D = w.d[seg];
    int local = bid - D.off;
    int per = D.nx * D.ny;
    int l = local / per;
    int rem = local - l * per;
    int kb = (rem % D.nx) * 32, nb = (rem / D.nx) * 32;

    const float* s = D.src + (size_t)l * D.K * D.N;
    unsigned short* d = D.dst + (size_t)l * D.ldd;
    int r = threadIdx.x >> 3, c4 = (threadIdx.x & 7) * 4;
    f32x4 v = *(const f32x4*)(s + (size_t)(kb + r) * D.N + nb + c4);
    #pragma unroll
    for (int j = 0; j < 4; ++j) t[c4 + j][r] = f2bf(v[j]);
    __syncthreads();
    u16x4 o;
    #pragma unroll
    for (int j = 0; j < 4; ++j) o[j] = t[r][c4 + j];
    *(u16x4*)(d + (size_t)(nb + r) * D.K + kb + c4) = o;
}

// ---------------------------------------------------------------------------
// cvt: tgt f32 -> x bf16
// ---------------------------------------------------------------------------
__global__ __launch_bounds__(256) void cvt_bf16(const float* __restrict__ src,
                                                unsigned short* __restrict__ dst)
{
    size_t i = ((size_t)blockIdx.x * 256 + threadIdx.x) * 8;
    f32x4 a = *(const f32x4*)(src + i);
    f32x4 b = *(const f32x4*)(src + i + 4);
    u16x8 t;
    #pragma unroll
    for (int j = 0; j < 4; ++j) { t[j] = f2bf(a[j]); t[4 + j] = f2bf(b[j]); }
    *(u16x8*)(dst + i) = t;
}

// ---------------------------------------------------------------------------
// GEMM device body: C[M x N] = A @ BT^T (+bias)(+relu), bf16, MFMA.
// BM=128, BN templated, BK=64, 256 threads (2x2 waves). XOR-swizzled LDS,
// single LDS buffer + register prefetch (tile t+1 loads under compute(t)).
// ---------------------------------------------------------------------------
template<int BN, bool BIAS, bool RELU>
__device__ __forceinline__ void gemm_body(
    const unsigned short* __restrict__ A, int lda, size_t m0,
    const unsigned short* __restrict__ BT, int n0,
    const float* __restrict__ bias,
    unsigned short* __restrict__ C, int ldc, int K)
{
    constexpr int NT = BN / 32;
    constexpr int BCH = BN / 32;
    __shared__ __align__(16) char As[128 * 128];
    __shared__ __align__(16) char Bs[BN * 128];

    const int tid = threadIdx.x;
    const int w = tid >> 6, l = tid & 63;
    const int lr = l & 15, lk = l >> 4;
    const int wm = w >> 1, wn = w & 1;

    f32x4 acc[4][NT] = {};
    u16x8 ra[4], rb[BCH];

    auto gload = [&](int k0) {
        #pragma unroll
        for (int i = 0; i < 4; ++i) {
            int cid = tid + i * 256, row = cid >> 3, kc = cid & 7;
            ra[i] = *(const u16x8*)(A + (m0 + row) * lda + k0 + kc * 8);
        }
        #pragma unroll
        for (int i = 0; i < BCH; ++i) {
            int fid = tid + i * 256, row = fid >> 3, kc = fid & 7;
            rb[i] = *(const u16x8*)(BT + (size_t)(n0 + row) * K + k0 + kc * 8);
        }
    };
    auto lstore = [&]() {
        #pragma unroll
        for (int i = 0; i < 4; ++i) {
            int cid = tid + i * 256, row = cid >> 3, kc = cid & 7;
            *(u16x8*)(As + ((row * 128 + kc * 16) ^ ((row & 7) << 4))) = ra[i];
        }
        #pragma unroll
        for (int i = 0; i < BCH; ++i) {
            int fid = tid + i * 256, row = fid >> 3, kc = fid & 7;
            *(u16x8*)(Bs + ((row * 128 + kc * 16) ^ ((row & 7) << 4))) = rb[i];
        }
    };

    const int nk = K >> 6;
    gload(0);
    for (int t = 0; t < nk; ++t) {
        lstore();
        __syncthreads();
        if (t + 1 < nk) gload((t + 1) << 6);
        #pragma unroll
        for (int s = 0; s < 2; ++s) {
            bf16x8 bfr[NT];
            #pragma unroll
            for (int nt = 0; nt < NT; ++nt) {
                int r = wn * (BN / 2) + nt * 16 + lr;
                bfr[nt] = *(const bf16x8*)(Bs + ((r * 128 + s * 64 + lk * 16) ^ ((r & 7) << 4)));
            }
            #pragma unroll
            for (int mt = 0; mt < 4; ++mt) {
                int r = wm * 64 + mt * 16 + lr;
                bf16x8 afr = *(const bf16x8*)(As + ((r * 128 + s * 64 + lk * 16) ^ ((r & 7) << 4)));
                #pragma unroll
                for (int nt = 0; nt < NT; ++nt)
                    acc[mt][nt] = __builtin_amdgcn_mfma_f32_16x16x32_bf16(afr, bfr[nt], acc[mt][nt], 0, 0, 0);
            }
        }
        __syncthreads();
    }
    #pragma unroll
    for (int nt = 0; nt < NT; ++nt) {
        int col = n0 + wn * (BN / 2) + nt * 16 + lr;
        float bv = BIAS ? bias[col] : 0.0f;
        #pragma unroll
        for (int mt = 0; mt < 4; ++mt) {
            #pragma unroll
            for (int j = 0; j < 4; ++j) {
                size_t row = m0 + (size_t)(wm * 64 + mt * 16 + lk * 4 + j);
                float v = acc[mt][nt][j] + bv;
                if (RELU) v = fmaxf(v, 0.0f);
                C[row * ldc + col] = f2bf(v);
            }
        }
    }
}

// standard GEMM: XCD-aware remap (bijective: all grids have nwg % 8 == 0),
// n-tile fast within an m-panel, each XCD owns contiguous m-panels.
template<int BN, bool BIAS, bool RELU>
__global__ __launch_bounds__(256) void gemm_bb(
    const unsigned short* __restrict__ A, int lda,
    const unsigned short* __restrict__ BT,
    const float* __restrict__ bias,
    unsigned short* __restrict__ C, int ldc, int K)
{
    const int hw = blockIdx.x + gridDim.x * blockIdx.y;
    const int nwg = gridDim.x * gridDim.y;
    const int logical = (hw & 7) * (nwg >> 3) + (hw >> 3);
    const int n0 = (logical % gridDim.x) * BN;
    const size_t m0 = (size_t)(logical / gridDim.x) * 128;
    gemm_body<BN, BIAS, RELU>(A, lda, m0, BT, n0, bias, C, ldc, K);
}

// merged hi/lo projection: grid (1, 2048); logical m-panels >= 1024 compute
// lo = los @ WlpT + blp, else hi = os @ WhpT + bhp. K=128, BN=128, ldc=128.
__global__ __launch_bounds__(256) void gemm_hilo(
    const unsigned short* __restrict__ os,
    const unsigned short* __restrict__ los,
    const unsigned short* __restrict__ tWhp,
    const unsigned short* __restrict__ tWlp,
    const float* __restrict__ bhp, const float* __restrict__ blp,
    unsigned short* __restrict__ hi, unsigned short* __restrict__ lo)
{
    const int hw = blockIdx.x + gridDim.x * blockIdx.y;
    const int nwg = gridDim.x * gridDim.y;
    const int logical = (hw & 7) * (nwg >> 3) + (hw >> 3);
    size_t mp = (size_t)logical;
    const unsigned short* A;
    const unsigned short* BT;
    const float* bias;
    unsigned short* C;
    if (mp < 1024) {
        A = os;  BT = tWhp; bias = bhp; C = hi;
    } else {
        A = los; BT = tWlp; bias = blp; C = lo; mp -= 1024;
    }
    gemm_body<128, true, false>(A, 128, mp * 128, BT, 0, bias, C, 128, 128);
}

// ---------------------------------------------------------------------------
// hifi_pool: grid union. Blocks [0,2048): windowed 4-token attention from
// qkv2 (row stride 512: [q|k|v|lq]). Blocks [2048,6144): 2x2 window pooling.
// ---------------------------------------------------------------------------
__global__ __launch_bounds__(256) void hifi_pool(
    const unsigned short* __restrict__ qkv,
    unsigned short* __restrict__ os,
    const unsigned short* __restrict__ x,
    unsigned short* __restrict__ xp)
{
    if (blockIdx.x < 2048) {
        int t = blockIdx.x * 256 + threadIdx.x;
        int wdw = t >> 4, h = (t >> 2) & 3, qi = t & 3;
        int bc = wdw >> 5, tw = wdw & 31;
        int rbase = bc * 128 + (tw >> 3) * 32 + (tw & 7) * 2;
        int qrow = rbase + ((qi >> 1) << 4) + (qi & 1);

        const unsigned short* qp = qkv + (size_t)qrow * 512 + h * 32;
        float q[32];
        #pragma unroll
        for (int c = 0; c < 4; ++c) {
            u16x8 v = *(const u16x8*)(qp + c * 8);
            #pragma unroll
            for (int j = 0; j < 8; ++j) q[c * 8 + j] = bf2f(v[j]);
        }
        float s4[4];
        #pragma unroll
        for (int j = 0; j < 4; ++j) {
            int kr = rbase + ((j >> 1) << 4) + (j & 1);
            const unsigned short* kp = qkv + (size_t)kr * 512 + 128 + h * 32;
            float d = 0.0f;
            #pragma unroll
            for (int c = 0; c < 4; ++c) {
                u16x8 v = *(const u16x8*)(kp + c * 8);
                #pragma unroll
                for (int jj = 0; jj < 8; ++jj) d += q[c * 8 + jj] * bf2f(v[jj]);
            }
            s4[j] = d * ATT_SCALE;
        }
        float mx = fmaxf(fmaxf(s4[0], s4[1]), fmaxf(s4[2], s4[3]));
        float den = 0.0f;
        #pragma unroll
        for (int j = 0; j < 4; ++j) { s4[j] = __expf(s4[j] - mx); den += s4[j]; }
        float inv = 1.0f / den;

        float o[32];
        #pragma unroll
        for (int i = 0; i < 32; ++i) o[i] = 0.0f;
        #pragma unroll
        for (int j = 0; j < 4; ++j) {
            int vr = rbase + ((j >> 1) << 4) + (j & 1);
            const unsigned short* vp = qkv + (size_t)vr * 512 + 256 + h * 32;
            float a = s4[j] * inv;
            #pragma unroll
            for (int c = 0; c < 4; ++c) {
                u16x8 v = *(const u16x8*)(vp + c * 8);
                #pragma unroll
                for (int jj = 0; jj < 8; ++jj) o[c * 8 + jj] += a * bf2f(v[jj]);
            }
        }
        unsigned short* op = os + (size_t)qrow * 128 + h * 32;
        #pragma unroll
        for (int c = 0; c < 4; ++c) {
            u16x8 v;
            #pragma unroll
            for (int j = 0; j < 8; ++j) v[j] = f2bf(o[c * 8 + j]);
            *(u16x8*)(op + c * 8) = v;
        }
    } else {
        int id = (blockIdx.x - 2048) * 256 + threadIdx.x;
        int p = id >> 5, c8 = (id & 31) * 8;
        int bc = p >> 5, tw = p & 31;
        int rbase = bc * 128 + (tw >> 3) * 32 + (tw & 7) * 2;
        const unsigned short* x0 = x + (size_t)rbase * 256 + c8;
        float a[8] = {};
        const int offs[4] = {0, 256, 16 * 256, 17 * 256};
        #pragma unroll
        for (int r = 0; r < 4; ++r) {
            u16x8 v = *(const u16x8*)(x0 + offs[r]);
            #pragma unroll
            for (int j = 0; j < 8; ++j) a[j] += bf2f(v[j]);
        }
        u16x8 o;
        #pragma unroll
        for (int j = 0; j < 8; ++j) o[j] = f2bf(a[j] * 0.25f);
        *(u16x8*)(xp + (size_t)p * 256 + c8) = o;
    }
}

// ---------------------------------------------------------------------------
// lofi: 128 queries vs 32 pooled kv per (bc, head). q from qkv2 (ldq=512).
// ---------------------------------------------------------------------------
__global__ __launch_bounds__(128) void lofi_attn(const unsigned short* __restrict__ qb,
                                                 int ldq,
                                                 const unsigned short* __restrict__ kvb,
                                                 unsigned short* __restrict__ ob)
{
    __shared__ float ks[32][36];
    __shared__ float vs[32][36];
    int bc = blockIdx.x >> 2, h = blockIdx.x & 3;
    int tid = threadIdx.x;

    #pragma unroll
    for (int i = 0; i < 2; ++i) {
        int fid = tid + i * 128;
        int row = fid >> 3, cc = (fid & 7) * 4;
        const unsigned short* kp = kvb + (size_t)(bc * 32 + row) * 256 + h * 32 + cc;
        u16x4 kk = *(const u16x4*)kp;
        u16x4 vv = *(const u16x4*)(kp + 128);
        #pragma unroll
        for (int j = 0; j < 4; ++j) { ks[row][cc + j] = bf2f(kk[j]); vs[row][cc + j] = bf2f(vv[j]); }
    }

    const unsigned short* qp = qb + (size_t)(bc * 128 + tid) * ldq + h * 32;
    float q[32];
    #pragma unroll
    for (int c = 0; c < 4; ++c) {
        u16x8 v = *(const u16x8*)(qp + c * 8);
        #pragma unroll
        for (int j = 0; j < 8; ++j) q[c * 8 + j] = bf2f(v[j]);
    }
    __syncthreads();

    float sc[32];
    #pragma unroll
    for (int tk = 0; tk < 32; ++tk) {
        float d = 0.0f;
        #pragma unroll
        for (int i = 0; i < 32; ++i) d += q[i] * ks[tk][i];
        sc[tk] = d * ATT_SCALE;
    }
    float mx = -1e30f;
    #pragma unroll
    for (int tk = 0; tk < 32; ++tk) mx = fmaxf(mx, sc[tk]);
    float den = 0.0f;
    #pragma unroll
    for (int tk = 0; tk < 32; ++tk) { sc[tk] = __expf(sc[tk] - mx); den += sc[tk]; }
    float inv = 1.0f / den;

    float o[32];
    #pragma unroll
    for (int i = 0; i < 32; ++i) o[i] = 0.0f;
    #pragma unroll
    for (int tk = 0; tk < 32; ++tk) {
        float a = sc[tk];
        #pragma unroll
        for (int i = 0; i < 32; ++i) o[i] += a * vs[tk][i];
    }
    unsigned short* op = ob + (size_t)(bc * 128 + tid) * 128 + h * 32;
    #pragma unroll
    for (int c = 0; c < 4; ++c) {
        u16x8 v;
        #pragma unroll
        for (int j = 0; j < 8; ++j) v[j] = f2bf(o[c * 8 + j] * inv);
        *(u16x8*)(op + c * 8) = v;
    }
}

// ---------------------------------------------------------------------------
// addln: one 64-lane wave per row (4 rows/block), lane holds 4 cols.
// MODE 0: x + [hi|lo] -> LN -> x bf16
// MODE 1: x + f       -> LN -> x bf16
// MODE 2: x + f -> LN2 -> LNf -> out f32 (fused tail, f32 precision)
// ---------------------------------------------------------------------------
template<int MODE>
__global__ __launch_bounds__(256) void addln(
    const unsigned short* __restrict__ x,
    const unsigned short* __restrict__ r1,
    const unsigned short* __restrict__ r2,
    const float* __restrict__ g, const float* __restrict__ b,
    const float* __restrict__ g2, const float* __restrict__ b2,
    unsigned short* __restrict__ xout, float* __restrict__ fout)
{
    size_t row = (size_t)blockIdx.x * 4 + (threadIdx.x >> 6);
    int l = threadIdx.x & 63;
    u16x4 xv = *(const u16x4*)(x + row * 256 + l * 4);
    f32x4 v;
    #pragma unroll
    for (int j = 0; j < 4; ++j) v[j] = bf2f(xv[j]);
    if (MODE == 0) {
        const unsigned short* rp = (l < 32) ? (r1 + row * 128 + l * 4)
                                            : (r2 + row * 128 + (l - 32) * 4);
        u16x4 rv = *(const u16x4*)rp;
        #pragma unroll
        for (int j = 0; j < 4; ++j) v[j] += bf2f(rv[j]);
    } else {
        u16x4 rv = *(const u16x4*)(r1 + row * 256 + l * 4);
        #pragma unroll
        for (int j = 0; j < 4; ++j) v[j] += bf2f(rv[j]);
    }
    float s = v[0] + v[1] + v[2] + v[3];
    float sq = v[0] * v[0] + v[1] * v[1] + v[2] * v[2] + v[3] * v[3];
    #pragma unroll
    for (int off = 32; off > 0; off >>= 1) { s += __shfl_xor(s, off); sq += __shfl_xor(sq, off); }
    float mean = s * (1.0f / 256.0f);
    float rstd = rsqrtf(sq * (1.0f / 256.0f) - mean * mean + 1e-5f);
    f32x4 gv = *(const f32x4*)(g + l * 4);
    f32x4 bv = *(const f32x4*)(b + l * 4);
    f32x4 o;
    #pragma unroll
    for (int j = 0; j < 4; ++j) o[j] = (v[j] - mean) * rstd * gv[j] + bv[j];
    if (MODE == 2) {
        float s2 = o[0] + o[1] + o[2] + o[3];
        float sq2 = o[0] * o[0] + o[1] * o[1] + o[2] * o[2] + o[3] * o[3];
        #pragma unroll
        for (int off = 32; off > 0; off >>= 1) { s2 += __shfl_xor(s2, off); sq2 += __shfl_xor(sq2, off); }
        float mean2 = s2 * (1.0f / 256.0f);
        float rstd2 = rsqrtf(sq2 * (1.0f / 256.0f) - mean2 * mean2 + 1e-5f);
        f32x4 g2v = *(const f32x4*)(g2 + l * 4);
        f32x4 b2v = *(const f32x4*)(b2 + l * 4);
        f32x4 f;
        #pragma unroll
        for (int j = 0; j < 4; ++j) f[j] = (o[j] - mean2) * rstd2 * g2v[j] + b2v[j];
        *(f32x4*)(fout + row * 256 + l * 4) = f;
    } else {
        u16x4 t;
        #pragma unroll
        for (int j = 0; j < 4; ++j) t[j] = f2bf(o[j]);
        *(u16x4*)(xout + row * 256 + l * 4) = t;
    }
}

// ---------------------------------------------------------------------------
extern "C" void kernel_launch(void* const* d_in, const int* in_sizes, int n_in,
                              void* d_out, int out_size, void* d_ws, size_t ws_size,
                              hipStream_t stream)
{
    (void)in_sizes; (void)n_in; (void)out_size; (void)ws_size;
    const float* tgt   = (const float*)d_in[0];
    const float* Wlq   = (const float*)d_in[1];
    const float* Wlkv  = (const float*)d_in[2];
    const float* Wlp   = (const float*)d_in[3];
    const float* blp   = (const float*)d_in[4];
    const float* Whqkv = (const float*)d_in[5];
    const float* Whp   = (const float*)d_in[6];
    const float* bhp   = (const float*)d_in[7];
    const float* W1    = (const float*)d_in[8];
    const float* b1    = (const float*)d_in[9];
    const float* W2    = (const float*)d_in[10];
    const float* b2    = (const float*)d_in[11];
    const float* ln1g  = (const float*)d_in[12];
    const float* ln1b  = (const float*)d_in[13];
    const float* ln2g  = (const float*)d_in[14];
    const float* ln2b  = (const float*)d_in[15];
    const float* lnfg  = (const float*)d_in[16];
    const float* lnfb  = (const float*)d_in[17];

    unsigned short* wsu = (unsigned short*)d_ws;
    // transposed bf16 weights: tQ = [Whqkv | Wlq] combined [L][512][256]
    unsigned short* tQ     = wsu;             // 2*512*256 = 262144
    unsigned short* tWhp   = wsu + 262144;    // 2*128*128 =  32768
    unsigned short* tWlkv  = wsu + 294912;    // 2*256*256 = 131072
    unsigned short* tWlp   = wsu + 425984;    // 2*128*128 =  32768
    unsigned short* tW1    = wsu + 458752;    // 2*512*256 = 262144
    unsigned short* tW2    = wsu + 720896;    // 2*256*512 = 262144
    unsigned short* x      = wsu + 983040;               // R*256
    unsigned short* qkv2   = x + RT * 256;               // R*512 [q|k|v|lq]
    unsigned short* f      = qkv2;                       // R*256 alias (qkv2 dead after lofi)
    unsigned short* xp     = qkv2 + RT * 512;            // 32768*256
    unsigned short* kv     = xp + 32768ull * 256;        // 32768*256
    unsigned short* hbuf   = kv + 32768ull * 256;        // R*512
    unsigned short* los    = hbuf;                       // R*128
    unsigned short* os     = hbuf + RT * 128;            // R*128
    unsigned short* hi     = hbuf + RT * 256;            // R*128
    unsigned short* lo     = hbuf + RT * 384;            // R*128
    // lifetime: {los,os,hi,lo} all dead after addln0; then hbuf holds h.

    // all weight transposes in one dispatch (960 blocks)
    W7 w;
    w.d[0] = { Whqkv, tQ,          256, 384, 131072,  8, 12,   0 };
    w.d[1] = { Wlq,   tQ + 98304,  256, 128, 131072,  8,  4, 192 };
    w.d[2] = { Whp,   tWhp,        128, 128,  16384,  4,  4, 256 };
    w.d[3] = { Wlkv,  tWlkv,       256, 256,  65536,  8,  8, 288 };
    w.d[4] = { Wlp,   tWlp,        128, 128,  16384,  4,  4, 416 };
    w.d[5] = { W1,    tW1,         256, 512, 131072,  8, 16, 448 };
    w.d[6] = { W2,    tW2,         512, 256, 131072, 16,  8, 704 };
    wprep_all<<<960, 256, 0, stream>>>(w);

    cvt_bf16<<<16384, 256, 0, stream>>>(tgt, x);

    for (int li = 0; li < 2; ++li) {
        // 1. qkv2 = x @ [Whqkv|Wlq]T  (R x 512, K=256; BN=128, nwg=4096)
        gemm_bb<128, false, false><<<dim3(4, 1024), 256, 0, stream>>>(
            x, 256, tQ + (size_t)li * 131072, nullptr, qkv2, 512, 256);
        // 2. hifi window attention + pool (grid union)
        hifi_pool<<<6144, 256, 0, stream>>>(qkv2, os, x, xp);
        // 3. kv = xp @ WlkvT   (M = 32768, BN=128, nwg=512)
        gemm_bb<128, false, false><<<dim3(2, 256), 256, 0, stream>>>(
            xp, 256, tWlkv + (size_t)li * 65536, nullptr, kv, 256, 256);
        // 4. lofi attention (q = qkv2 cols 384.., stride 512) -> los
        lofi_attn<<<4096, 128, 0, stream>>>(qkv2 + 384, 512, kv, los);
        // 5. merged hi/lo projection (BN=128, nwg=2048)
        gemm_hilo<<<dim3(1, 2048), 256, 0, stream>>>(
            os, los, tWhp + (size_t)li * 16384, tWlp + (size_t)li * 16384,
            bhp + li * 128, blp + li * 128, hi, lo);
        // 6. x = LN(x + [hi|lo])
        addln<0><<<32768, 256, 0, stream>>>(x, hi, lo, ln1g + li * 256, ln1b + li * 256,
                                            nullptr, nullptr, x, nullptr);
        // 7. h = relu(x @ W1T + b1)   (BN=128, nwg=4096)
        gemm_bb<128, true, true><<<dim3(4, 1024), 256, 0, stream>>>(
            x, 256, tW1 + (size_t)li * 131072, b1 + li * 512, hbuf, 512, 256);
        // 8. f = h @ W2T + b2   (f aliases qkv2[0:R*256]; BN=128, nwg=2048)
        gemm_bb<128, true, false><<<dim3(2, 1024), 256, 0, stream>>>(
            hbuf, 512, tW2 + (size_t)li * 131072, b2 + li * 256, f, 256, 512);
        // 9. x = LN(x + f)  |  layer 1: fused LN2 + final LN -> f32 out
        if (li == 0) {
            addln<1><<<32768, 256, 0, stream>>>(x, f, nullptr, ln2g, ln2b,
                                                nullptr, nullptr, x, nullptr);
        } else {
            addln<2><<<32768, 256, 0, stream>>>(x, f, nullptr, ln2g + 256, ln2b + 256,
                                                lnfg, lnfb, nullptr, (float*)d_out);
        }
    }
}